// Round 1
// baseline (2624.223 us; speedup 1.0000x reference)
//
#include <hip/hip_runtime.h>
#include <math.h>

#define B_ 4
#define C_ 64
#define H_ 64
#define W_ 64
#define HW 4096      // H*W
#define L_ 4096
#define D_ 576       // C*9
#define MW 256       // mask width
#define SCALE 10.0f
#define EPS 1e-4f

// mp[b, p] = avg 4x4 block of mask
__global__ __launch_bounds__(256) void k_mp(const float* __restrict__ mask, float* __restrict__ mp) {
  int idx = blockIdx.x * 256 + threadIdx.x;      // b*4096 + p
  int b = idx >> 12, p = idx & 4095;
  int y = p >> 6, x = p & 63;
  const float* mb = mask + (size_t)b * MW * MW;
  float s = 0.f;
  #pragma unroll
  for (int i = 0; i < 4; ++i)
    #pragma unroll
    for (int j = 0; j < 4; ++j)
      s += mb[(y * 4 + i) * MW + x * 4 + j];
  mp[idx] = s * (1.f / 16.f);
}

// m0[l, t] = zero-padded 3x3 patch of mp batch 0
__global__ __launch_bounds__(256) void k_m0(const float* __restrict__ mp, float* __restrict__ m0) {
  int idx = blockIdx.x * 256 + threadIdx.x;      // l*9 + t
  int l = idx / 9, t = idx - l * 9;
  int ly = l >> 6, lx = l & 63;
  int i = t / 3, j = t - i * 3;
  int yy = ly + i - 1, xx = lx + j - 1;
  float v = 0.f;
  if ((unsigned)yy < 64u && (unsigned)xx < 64u) v = mp[(yy << 6) + xx];
  m0[idx] = v;
}

// fm = f * (1 - mp)
__global__ __launch_bounds__(256) void k_fm(const float* __restrict__ f, const float* __restrict__ mp,
                                            float* __restrict__ fm) {
  int idx = blockIdx.x * 256 + threadIdx.x;      // b*C*HW + c*HW + p
  int p = idx & 4095;
  int b = idx >> 18;
  fm[idx] = f[idx] * (1.f - mp[(b << 12) + p]);
}

// im2col: outp[l*576 + c*9 + t] = img[c, ly+i-1, lx+j-1] (* m0[l*9+t] if m0)
__global__ __launch_bounds__(256) void k_patch(const float* __restrict__ img,
                                               const float* __restrict__ m0,
                                               float* __restrict__ outp) {
  int idx = blockIdx.x * 256 + threadIdx.x;      // l*576 + d
  int l = idx / D_;
  int d = idx - l * D_;
  int c = d / 9, t = d - c * 9;
  int ly = l >> 6, lx = l & 63;
  int i = t / 3, j = t - i * 3;
  int yy = ly + i - 1, xx = lx + j - 1;
  float v = 0.f;
  if ((unsigned)yy < 64u && (unsigned)xx < 64u) v = img[(c << 12) + (yy << 6) + xx];
  if (m0) v *= m0[l * 9 + t];
  outp[idx] = v;
}

// norm[l] = sqrt(sum_d w[l,d]^2 + eps), one wave per l
__global__ __launch_bounds__(256) void k_norm(const float* __restrict__ wbuf, float* __restrict__ normv) {
  int l = blockIdx.x * 4 + (threadIdx.x >> 6);
  int lane = threadIdx.x & 63;
  const float* row = wbuf + (size_t)l * D_;
  float s = 0.f;
  for (int i = lane; i < D_; i += 64) { float v = row[i]; s += v * v; }
  #pragma unroll
  for (int off = 32; off; off >>= 1) s += __shfl_down(s, off);
  if (lane == 0) normv[l] = sqrtf(s + EPS);
}

// score_T[q, l] = dot(A[q,:], Bm[l,:]) / normv[l]   (K = 576, both row-major)
__global__ __launch_bounds__(256) void k_gemm_nt(const float* __restrict__ A,
                                                 const float* __restrict__ Bm,
                                                 const float* __restrict__ normv,
                                                 float* __restrict__ Cm) {
  __shared__ float As[16][132];
  __shared__ float Bs[16][132];
  int bm = blockIdx.y * 128, bn = blockIdx.x * 128;
  int tid = threadIdx.x;
  int tr = tid >> 4, tc = tid & 15;
  float acc[8][8] = {};
  for (int k0 = 0; k0 < D_; k0 += 16) {
    #pragma unroll
    for (int i = 0; i < 8; ++i) {
      int idx = tid + i * 256;                   // 0..2047
      int r = idx >> 4, cc = idx & 15;           // r 0..127, cc 0..15
      As[cc][r] = A[(size_t)(bm + r) * D_ + k0 + cc];
      Bs[cc][r] = Bm[(size_t)(bn + r) * D_ + k0 + cc];
    }
    __syncthreads();
    #pragma unroll
    for (int kk = 0; kk < 16; ++kk) {
      float4 a0 = *(const float4*)&As[kk][tr * 8];
      float4 a1 = *(const float4*)&As[kk][tr * 8 + 4];
      float4 b0 = *(const float4*)&Bs[kk][tc * 8];
      float4 b1 = *(const float4*)&Bs[kk][tc * 8 + 4];
      float a[8]  = {a0.x, a0.y, a0.z, a0.w, a1.x, a1.y, a1.z, a1.w};
      float bb[8] = {b0.x, b0.y, b0.z, b0.w, b1.x, b1.y, b1.z, b1.w};
      #pragma unroll
      for (int i = 0; i < 8; ++i)
        #pragma unroll
        for (int j = 0; j < 8; ++j)
          acc[i][j] += a[i] * bb[j];
    }
    __syncthreads();
  }
  #pragma unroll
  for (int i = 0; i < 8; ++i) {
    int m = bm + tr * 8 + i;
    #pragma unroll
    for (int j = 0; j < 8; ++j) {
      int n = bn + tc * 8 + j;
      Cm[(size_t)m * L_ + n] = acc[i][j] / normv[n];
    }
  }
}

// row softmax (x10) + argmax; attn written in-place, offsets as float
__global__ __launch_bounds__(256) void k_softmax(float* __restrict__ score, float* __restrict__ offs) {
  int q = blockIdx.x;
  float* row = score + (size_t)q * L_;
  int tid = threadIdx.x;
  int wid = tid >> 6, lane = tid & 63;
  __shared__ float smax[4]; __shared__ int sidx[4]; __shared__ float ssum[4];

  float v[16];
  float vmax = -3.4e38f; int vidx = 0;
  #pragma unroll
  for (int i = 0; i < 16; ++i) {
    int idx = tid + i * 256;
    v[i] = row[idx];
    if (v[i] > vmax) { vmax = v[i]; vidx = idx; }
  }
  #pragma unroll
  for (int off = 32; off; off >>= 1) {
    float ov = __shfl_down(vmax, off);
    int   oi = __shfl_down(vidx, off);
    if (ov > vmax || (ov == vmax && oi < vidx)) { vmax = ov; vidx = oi; }
  }
  if (lane == 0) { smax[wid] = vmax; sidx[wid] = vidx; }
  __syncthreads();
  if (tid == 0) {
    vmax = smax[0]; vidx = sidx[0];
    for (int w = 1; w < 4; ++w)
      if (smax[w] > vmax || (smax[w] == vmax && sidx[w] < vidx)) { vmax = smax[w]; vidx = sidx[w]; }
    smax[0] = vmax; sidx[0] = vidx;
  }
  __syncthreads();
  vmax = smax[0];

  float s = 0.f;
  #pragma unroll
  for (int i = 0; i < 16; ++i) { v[i] = expf((v[i] - vmax) * SCALE); s += v[i]; }
  #pragma unroll
  for (int off = 32; off; off >>= 1) s += __shfl_down(s, off);
  if (lane == 0) ssum[wid] = s;
  __syncthreads();
  if (tid == 0) ssum[0] = ssum[0] + ssum[1] + ssum[2] + ssum[3];
  __syncthreads();
  float inv = 1.f / ssum[0];
  #pragma unroll
  for (int i = 0; i < 16; ++i) row[tid + i * 256] = v[i] * inv;
  if (tid == 0) offs[q] = (float)sidx[0];
}

// G[q, d] = sum_l attn[q, l] * wbuf[l, d]   (M=4096, N=576, K=4096)
__global__ __launch_bounds__(256) void k_gemm_nn(const float* __restrict__ A,
                                                 const float* __restrict__ Bm,
                                                 float* __restrict__ Cm) {
  __shared__ float As[32][68];
  __shared__ float Bs[32][68];
  int bm = blockIdx.y * 64, bn = blockIdx.x * 64;
  int tid = threadIdx.x;
  int tr = tid >> 4, tc = tid & 15;
  float acc[4][4] = {};
  for (int k0 = 0; k0 < L_; k0 += 32) {
    #pragma unroll
    for (int i = 0; i < 8; ++i) {
      int idx = tid + i * 256;                   // 0..2047
      int r = idx >> 5, kk = idx & 31;           // A: 64 rows x 32 k
      As[kk][r] = A[(size_t)(bm + r) * L_ + k0 + kk];
      int n = idx & 63, kk2 = idx >> 6;          // B: 32 k x 64 n
      Bs[kk2][n] = Bm[(size_t)(k0 + kk2) * D_ + bn + n];
    }
    __syncthreads();
    #pragma unroll
    for (int kk = 0; kk < 32; ++kk) {
      float4 av = *(const float4*)&As[kk][tr * 4];
      float4 bv = *(const float4*)&Bs[kk][tc * 4];
      float a[4]  = {av.x, av.y, av.z, av.w};
      float bb[4] = {bv.x, bv.y, bv.z, bv.w};
      #pragma unroll
      for (int i = 0; i < 4; ++i)
        #pragma unroll
        for (int j = 0; j < 4; ++j)
          acc[i][j] += a[i] * bb[j];
    }
    __syncthreads();
  }
  #pragma unroll
  for (int i = 0; i < 4; ++i) {
    int m = bm + tr * 4 + i;
    #pragma unroll
    for (int j = 0; j < 4; ++j)
      Cm[(size_t)m * D_ + bn + tc * 4 + j] = acc[i][j];
  }
}

// y[c, yy, xx] = sum_t G[(yy+1-i)*64 + (xx+1-j), c*9+t]
__global__ __launch_bounds__(256) void k_fold(const float* __restrict__ G, float* __restrict__ yout) {
  int idx = blockIdx.x * 256 + threadIdx.x;      // c*4096 + p
  int c = idx >> 12, p = idx & 4095;
  int yy = p >> 6, xx = p & 63;
  float s = 0.f;
  #pragma unroll
  for (int t = 0; t < 9; ++t) {
    int i = t / 3, j = t - (t / 3) * 3;
    int qy = yy + 1 - i, qx = xx + 1 - j;
    if ((unsigned)qy < 64u && (unsigned)qx < 64u)
      s += G[(size_t)((qy << 6) + qx) * D_ + c * 9 + t];
  }
  yout[idx] = s;
}

extern "C" void kernel_launch(void* const* d_in, const int* in_sizes, int n_in,
                              void* d_out, int out_size, void* d_ws, size_t ws_size,
                              hipStream_t stream) {
  const float* b_in = (const float*)d_in[0];
  const float* f_in = (const float*)d_in[1];
  const float* mask = (const float*)d_in[2];
  float* out = (float*)d_out;

  float* mp    = (float*)d_ws;            // 16384
  float* fm    = mp + 16384;              // 1048576
  float* m0    = fm + 1048576;            // 36864
  float* wbuf  = m0 + 36864;              // 2359296
  float* fpbuf = wbuf + 2359296;          // 2359296
  float* normv = fpbuf + 2359296;         // 4096
  float* Gbuf  = normv + 4096;            // 2359296
  float* score = Gbuf + 2359296;          // 16777216  (~100 MB total)

  k_mp<<<64, 256, 0, stream>>>(mask, mp);
  k_m0<<<144, 256, 0, stream>>>(mp, m0);
  k_fm<<<4096, 256, 0, stream>>>(f_in, mp, fm);

  for (int b = 0; b < B_; ++b) {
    k_patch<<<9216, 256, 0, stream>>>(b_in + (size_t)b * C_ * HW, m0, wbuf);
    k_norm<<<1024, 256, 0, stream>>>(wbuf, normv);
    k_patch<<<9216, 256, 0, stream>>>(fm + (size_t)b * C_ * HW, nullptr, fpbuf);
    k_gemm_nt<<<dim3(32, 32), 256, 0, stream>>>(fpbuf, wbuf, normv, score);
    k_softmax<<<4096, 256, 0, stream>>>(score, out + (size_t)B_ * C_ * HW + (size_t)b * HW);
    k_gemm_nn<<<dim3(9, 64), 256, 0, stream>>>(score, wbuf, Gbuf);
    k_fold<<<1024, 256, 0, stream>>>(Gbuf, out + (size_t)b * C_ * HW);
  }
}